// Round 1
// baseline (1337.803 us; speedup 1.0000x reference)
//
#include <hip/hip_runtime.h>
#include <math.h>

// DecoderCell (LFADS-like) fused kernel — Round 1: f32 VALU baseline.
// B=65536 rows, each block handles RT=64 rows, NT=512 threads (8 waves).
// Phases per block: stage con_input/con_state -> con GRU -> co linear +
// reparam -> stage gen_state -> gen GRU (2 column passes) -> factor GEMM.
// A-tiles live in LDS with a 16B-block XOR swizzle (slot = k4 ^ (r&7)) so
// float4 reads by 16 rows land 2-way max (free). Weights staged per
// (gate, k0) as [32][128+4] chunks, read as float4 broadcast.

#define NT 512
#define RT 64

#define XD 272
#define HD 420

#define OFF_CON 200
#define OFF_COM 328
#define OFF_COS 332
#define OFF_GIN 336
#define OFF_FAC 356

// LDS strides in dwords: round_up(K,32) + 8 (rows stay 16B aligned, banks spread)
#define ST_A 328   // K=320 (con_input)
#define ST_H 136   // K=128 (con_state)
#define ST_G 232   // K=200 -> padded data region 224 + 8
#define ST_GI 24   // K=20  (gen_input, unswizzled)
#define ST_W 132   // weight chunk [32][128+4]

// pool offsets (dwords)
#define P_W   0                  // 32*132 = 4224
#define P_GI  4224               // 64*24  = 1536
#define P_INV 5760               // 64
#define P_R   5824               // big region: 29696 dw
#define P_A   P_R                // 64*328 = 20992 (con phase)
#define P_H   (P_R + 20992)      // 64*136 = 8704  (con phase)
#define P_HN  P_R                // reuses dead sA (after con gi)
#define P_G   P_R                // 64*232 = 14848 (gen phase, after co)
#define P_GN  (P_R + 14848)      // 64*232 = 14848
#define POOL_DW (P_R + 29696)    // 35520 dw = 142,080 B LDS

__device__ __forceinline__ int swz(int r, int k) {
  // dword offset within a row: XOR the 16B-block index with (row&7)
  return (((k >> 2) ^ (r & 7)) << 2) | (k & 3);
}

__device__ __forceinline__ float sigf(float v) {
  return 1.0f / (1.0f + expf(-v));
}

// Stage W[n0+nn][k0+kk] (row-major [nRows][K]) -> sW[kk][nn], zero-filled OOB.
__device__ __forceinline__ void stage_w(float* __restrict__ sp, const float* __restrict__ W,
                                        int nRows, int K, int n0, int k0, int tid) {
  for (int idx = tid; idx < 32 * 128; idx += NT) {
    int kk = idx & 31, nn = idx >> 5;
    int n = n0 + nn, k = k0 + kk;
    float v = (n < nRows && k < K) ? W[(size_t)n * K + k] : 0.0f;
    sp[P_W + kk * ST_W + nn] = v;
  }
}

// acc[i][j] += A[rg+16i][k0..k0+31] dot W[k][cg*4+j] for one 32-k chunk.
__device__ __forceinline__ void mm_chunk(const float* __restrict__ sp, int aBase, int stA,
                                         int rg, int cg, int k0, float (&acc)[4][4]) {
  const int k4base = k0 >> 2;
  #pragma unroll
  for (int b = 0; b < 8; ++b) {
    float4 a[4], w[4];
    #pragma unroll
    for (int i = 0; i < 4; ++i) {
      int r = rg + 16 * i;
      int slot = (k4base + b) ^ (r & 7);
      a[i] = *(const float4*)&sp[aBase + r * stA + (slot << 2)];
    }
    #pragma unroll
    for (int q = 0; q < 4; ++q)
      w[q] = *(const float4*)&sp[P_W + (b * 4 + q) * ST_W + (cg << 2)];
    #pragma unroll
    for (int i = 0; i < 4; ++i) {
      float avv[4] = { a[i].x, a[i].y, a[i].z, a[i].w };
      #pragma unroll
      for (int q = 0; q < 4; ++q) {
        acc[i][0] = fmaf(avv[q], w[q].x, acc[i][0]);
        acc[i][1] = fmaf(avv[q], w[q].y, acc[i][1]);
        acc[i][2] = fmaf(avv[q], w[q].z, acc[i][2]);
        acc[i][3] = fmaf(avv[q], w[q].w, acc[i][3]);
      }
    }
  }
}

__global__ __launch_bounds__(NT, 2) void decoder_kernel(
    const float* __restrict__ x, const float* __restrict__ h0, const float* __restrict__ eps,
    const float* __restrict__ gen_w_ih, const float* __restrict__ gen_w_hh,
    const float* __restrict__ gen_b_ih, const float* __restrict__ gen_b_hh,
    const float* __restrict__ con_w_ih, const float* __restrict__ con_w_hh,
    const float* __restrict__ con_b_ih, const float* __restrict__ con_b_hh,
    const float* __restrict__ co_w, const float* __restrict__ co_b,
    const float* __restrict__ fac_w, float* __restrict__ out)
{
  __shared__ __align__(16) float sp[POOL_DW];
  const int tid = threadIdx.x;
  const int rbase = blockIdx.x * RT;
  const int rg = tid & 15;   // row group: rows rg, rg+16, rg+32, rg+48
  const int cg = tid >> 4;   // col group: cols cg*4 .. cg*4+3 (0..31)

  // ---- stage con_input (x[:,0:256] ++ factor=h0[:,356:420]) and con_state_old
  for (int idx = tid; idx < RT * 256; idx += NT) {
    int r = idx >> 8, k = idx & 255;
    sp[P_A + r * ST_A + swz(r, k)] = x[(size_t)(rbase + r) * XD + k];
  }
  for (int idx = tid; idx < RT * 64; idx += NT) {
    int r = idx >> 6, k = idx & 63;
    sp[P_A + r * ST_A + swz(r, 256 + k)] = h0[(size_t)(rbase + r) * HD + OFF_FAC + k];
  }
  for (int idx = tid; idx < RT * 128; idx += NT) {
    int r = idx >> 7, k = idx & 127;
    sp[P_H + r * ST_H + swz(r, k)] = h0[(size_t)(rbase + r) * HD + OFF_CON + k];
  }
  __syncthreads();

  float accI[3][4][4], accH[3][4][4];
  #pragma unroll
  for (int g = 0; g < 3; ++g)
    #pragma unroll
    for (int i = 0; i < 4; ++i)
      #pragma unroll
      for (int j = 0; j < 4; ++j) { accI[g][i][j] = 0.f; accH[g][i][j] = 0.f; }

  // ---- controller GRU gate GEMMs (cols = g*128 + cg*4+j)
  #pragma unroll
  for (int g = 0; g < 3; ++g) {
    for (int k0 = 0; k0 < 320; k0 += 32) {
      stage_w(sp, con_w_ih, 384, 320, g * 128, k0, tid);
      __syncthreads();
      mm_chunk(sp, P_A, ST_A, rg, cg, k0, accI[g]);
      __syncthreads();
    }
    for (int k0 = 0; k0 < 128; k0 += 32) {
      stage_w(sp, con_w_hh, 384, 128, g * 128, k0, tid);
      __syncthreads();
      mm_chunk(sp, P_H, ST_H, rg, cg, k0, accH[g]);
      __syncthreads();
    }
  }

  // ---- controller GRU elementwise -> con_state_new (sHn + out[200:328])
  #pragma unroll
  for (int i = 0; i < 4; ++i) {
    int r = rg + 16 * i;
    size_t orow = (size_t)(rbase + r) * HD;
    #pragma unroll
    for (int j = 0; j < 4; ++j) {
      int c = (cg << 2) + j;
      float ir  = accI[0][i][j] + con_b_ih[c];
      float iz  = accI[1][i][j] + con_b_ih[128 + c];
      float inn = accI[2][i][j] + con_b_ih[256 + c];
      float hr  = accH[0][i][j] + con_b_hh[c];
      float hz  = accH[1][i][j] + con_b_hh[128 + c];
      float hn  = accH[2][i][j] + con_b_hh[256 + c];
      float rr = sigf(ir + hr);
      float zz = sigf(iz + hz);
      float nn = tanhf(inn + rr * hn);
      float hold = sp[P_H + r * ST_H + swz(r, c)];
      float hv = (1.f - zz) * nn + zz * hold;
      hv = fminf(fmaxf(hv, -5.f), 5.f);
      out[orow + OFF_CON + c] = hv;
      sp[P_HN + r * ST_H + swz(r, c)] = hv;
    }
  }
  __syncthreads();

  // ---- co linear + reparameterization (thread t: row t>>3, col t&7)
  {
    int r = tid >> 3, n = tid & 7;
    float acc = co_b[n];
    for (int k = 0; k < 128; ++k)
      acc = fmaf(sp[P_HN + r * ST_H + swz(r, k)], co_w[n * 128 + k], acc);
    int lane = tid & 63;
    float lv = __shfl(acc, lane | 4, 64);   // partner holds logvar (n+4)
    if (n < 4) {
      float stdv = expf(0.5f * lv);
      float ov = fmaf(stdv, eps[(size_t)(rbase + r) * 4 + n], acc);
      size_t orow = (size_t)(rbase + r) * HD;
      out[orow + OFF_COM + n] = acc;
      out[orow + OFF_COS + n] = stdv;
      out[orow + OFF_GIN + n] = ov;
      sp[P_GI + r * ST_GI + n] = ov;
    }
  }
  // ext part of gen_input
  for (int idx = tid; idx < RT * 16; idx += NT) {
    int r = idx >> 4, e = idx & 15;
    float v = x[(size_t)(rbase + r) * XD + 256 + e];
    sp[P_GI + r * ST_GI + 4 + e] = v;
    out[(size_t)(rbase + r) * HD + OFF_GIN + 4 + e] = v;
  }
  __syncthreads();

  // ---- stage gen_state_old (zero-padded k in [200,224)), zero sGn pad
  for (int idx = tid; idx < RT * 224; idx += NT) {
    int r = idx / 224, k = idx - r * 224;
    float v = (k < 200) ? h0[(size_t)(rbase + r) * HD + k] : 0.0f;
    sp[P_G + r * ST_G + swz(r, k)] = v;
  }
  for (int idx = tid; idx < RT * 24; idx += NT) {
    int r = idx / 24, k = 200 + (idx - r * 24);
    sp[P_GN + r * ST_G + swz(r, k)] = 0.0f;
  }
  __syncthreads();

  // ---- generator GRU: two column passes (cols p*128 + cg*4+j, valid < 200)
  for (int p = 0; p < 2; ++p) {
    #pragma unroll
    for (int g = 0; g < 3; ++g)
      #pragma unroll
      for (int i = 0; i < 4; ++i)
        #pragma unroll
        for (int j = 0; j < 4; ++j) { accI[g][i][j] = 0.f; accH[g][i][j] = 0.f; }

    #pragma unroll
    for (int g = 0; g < 3; ++g) {
      // gi: K=20, A = gen_input (unswizzled)
      stage_w(sp, gen_w_ih, 600, 20, g * 200 + p * 128, 0, tid);
      __syncthreads();
      #pragma unroll
      for (int kk = 0; kk < 20; ++kk) {
        float4 w = *(const float4*)&sp[P_W + kk * ST_W + (cg << 2)];
        #pragma unroll
        for (int i = 0; i < 4; ++i) {
          float av = sp[P_GI + (rg + 16 * i) * ST_GI + kk];
          accI[g][i][0] = fmaf(av, w.x, accI[g][i][0]);
          accI[g][i][1] = fmaf(av, w.y, accI[g][i][1]);
          accI[g][i][2] = fmaf(av, w.z, accI[g][i][2]);
          accI[g][i][3] = fmaf(av, w.w, accI[g][i][3]);
        }
      }
      __syncthreads();
      // gh: K=200 (chunks zero-padded to 224)
      for (int k0 = 0; k0 < 224; k0 += 32) {
        stage_w(sp, gen_w_hh, 600, 200, g * 200 + p * 128, k0, tid);
        __syncthreads();
        mm_chunk(sp, P_G, ST_G, rg, cg, k0, accH[g]);
        __syncthreads();
      }
    }
    // elementwise -> gen_state_new (sGn + out[0:200])
    #pragma unroll
    for (int i = 0; i < 4; ++i) {
      int r = rg + 16 * i;
      size_t orow = (size_t)(rbase + r) * HD;
      #pragma unroll
      for (int j = 0; j < 4; ++j) {
        int c = p * 128 + (cg << 2) + j;
        if (c < 200) {
          float ir  = accI[0][i][j] + gen_b_ih[c];
          float iz  = accI[1][i][j] + gen_b_ih[200 + c];
          float inn = accI[2][i][j] + gen_b_ih[400 + c];
          float hr  = accH[0][i][j] + gen_b_hh[c];
          float hz  = accH[1][i][j] + gen_b_hh[200 + c];
          float hn  = accH[2][i][j] + gen_b_hh[400 + c];
          float rr = sigf(ir + hr);
          float zz = sigf(iz + hz);
          float nn = tanhf(inn + rr * hn);
          float hold = sp[P_G + r * ST_G + swz(r, c)];
          float hv = (1.f - zz) * nn + zz * hold;
          hv = fminf(fmaxf(hv, -5.f), 5.f);
          out[orow + c] = hv;
          sp[P_GN + r * ST_G + swz(r, c)] = hv;
        }
      }
    }
    __syncthreads();
  }

  // ---- factor = gen_state_new @ normed(fac_w)^T  (64 cols; cg<16 active)
  if (tid < 64) {
    float ss = 0.f;
    for (int k = 0; k < 200; ++k) { float v = fac_w[tid * 200 + k]; ss = fmaf(v, v, ss); }
    sp[P_INV + tid] = 1.0f / fmaxf(sqrtf(ss), 1e-12f);
  }
  __syncthreads();

  float accF[4][4];
  #pragma unroll
  for (int i = 0; i < 4; ++i)
    #pragma unroll
    for (int j = 0; j < 4; ++j) accF[i][j] = 0.f;

  for (int k0 = 0; k0 < 224; k0 += 32) {
    for (int idx = tid; idx < 32 * 128; idx += NT) {
      int kk = idx & 31, nn = idx >> 5;
      int k = k0 + kk;
      float v = (nn < 64 && k < 200) ? fac_w[nn * 200 + k] * sp[P_INV + nn] : 0.0f;
      sp[P_W + kk * ST_W + nn] = v;
    }
    __syncthreads();
    if (cg < 16) mm_chunk(sp, P_GN, ST_G, rg, cg, k0, accF);
    __syncthreads();
  }
  if (cg < 16) {
    #pragma unroll
    for (int i = 0; i < 4; ++i) {
      int r = rg + 16 * i;
      size_t orow = (size_t)(rbase + r) * HD;
      #pragma unroll
      for (int j = 0; j < 4; ++j)
        out[orow + OFF_FAC + (cg << 2) + j] = accF[i][j];
    }
  }
}

extern "C" void kernel_launch(void* const* d_in, const int* in_sizes, int n_in,
                              void* d_out, int out_size, void* d_ws, size_t ws_size,
                              hipStream_t stream) {
  const float* x        = (const float*)d_in[0];
  const float* h0       = (const float*)d_in[1];
  const float* eps      = (const float*)d_in[2];
  const float* gen_w_ih = (const float*)d_in[3];
  const float* gen_w_hh = (const float*)d_in[4];
  const float* gen_b_ih = (const float*)d_in[5];
  const float* gen_b_hh = (const float*)d_in[6];
  const float* con_w_ih = (const float*)d_in[7];
  const float* con_w_hh = (const float*)d_in[8];
  const float* con_b_ih = (const float*)d_in[9];
  const float* con_b_hh = (const float*)d_in[10];
  const float* co_w     = (const float*)d_in[11];
  const float* co_b     = (const float*)d_in[12];
  const float* fac_w    = (const float*)d_in[13];
  float* out = (float*)d_out;

  int nrows = in_sizes[2] / 4;      // eps is (B,4)
  int grid = nrows / RT;            // 65536/64 = 1024
  hipLaunchKernelGGL(decoder_kernel, dim3(grid), dim3(NT), 0, stream,
                     x, h0, eps, gen_w_ih, gen_w_hh, gen_b_ih, gen_b_hh,
                     con_w_ih, con_w_hh, con_b_ih, con_b_hh, co_w, co_b, fac_w, out);
}

// Round 2
// 329.877 us; speedup vs baseline: 4.0555x; 4.0555x over previous
//
#include <hip/hip_runtime.h>
#include <math.h>

// DecoderCell fused kernel — Round 2: bf16 MFMA for all GEMMs.
// Weights pre-converted to bf16 in d_ws (prepass), read as B-fragments
// directly from global (L2-hot). Activations staged in LDS bf16 with
// 2-way-free strides. co-linear + reparam kept in f32 VALU for precision.

#define NT 512
#define RT 64
#define XD 272
#define HD 420

typedef unsigned short ushort_t;
typedef __attribute__((ext_vector_type(8))) short bf8;
typedef __attribute__((ext_vector_type(4))) float f4;
typedef __attribute__((ext_vector_type(4))) unsigned short us4;

// ws layout (bf16 element offsets)
#define WS_W1 0         // con_w_ih [384][320]
#define WS_W2 122880    // con_w_hh [384][128]
#define WS_W3 172032    // gen_w_ih [608][32]  (K 20->32 pad, rows 600-607 zero)
#define WS_W4 191488    // gen_w_hh [608][224] (K 200->224 pad, rows 600-607 zero)
#define WS_W5 327680    // normed fac_w [64][224]
#define WS_TOT 342016

// LDS strides (elements); all chosen so 16-row frag reads are <=2-way banked
#define STA 328
#define STH 136
#define STG 232
#define STGI 40
#define SHN 132  // f32 dwords

__device__ __forceinline__ ushort_t f2bf(float f) {
  union { float f; unsigned u; } v; v.f = f;
  unsigned r = v.u + 0x7FFFu + ((v.u >> 16) & 1u);
  return (ushort_t)(r >> 16);
}
__device__ __forceinline__ us4 f2bf4(f4 v) {
  us4 b; b.x = f2bf(v.x); b.y = f2bf(v.y); b.z = f2bf(v.z); b.w = f2bf(v.w); return b;
}
__device__ __forceinline__ float sigf(float x) { return 1.0f / (1.0f + __expf(-x)); }
__device__ __forceinline__ float tanhf_(float x) { float e = __expf(2.0f * x); return 1.0f - 2.0f / (e + 1.0f); }

#define MFMA(a, b, c) __builtin_amdgcn_mfma_f32_16x16x32_bf16((a), (b), (c), 0, 0, 0)

__global__ void prep_w(const float* __restrict__ cw1, const float* __restrict__ cw2,
                       const float* __restrict__ gw3, const float* __restrict__ gw4,
                       ushort_t* __restrict__ ws) {
  int tid = blockIdx.x * blockDim.x + threadIdx.x;
  int np = gridDim.x * blockDim.x;
  for (int i = tid; i < 384 * 320; i += np) ws[WS_W1 + i] = f2bf(cw1[i]);
  for (int i = tid; i < 384 * 128; i += np) ws[WS_W2 + i] = f2bf(cw2[i]);
  for (int i = tid; i < 608 * 32; i += np) {
    int n = i >> 5, k = i & 31;
    ws[WS_W3 + i] = (n < 600 && k < 20) ? f2bf(gw3[n * 20 + k]) : (ushort_t)0;
  }
  for (int i = tid; i < 608 * 224; i += np) {
    int n = i / 224, k = i - n * 224;
    ws[WS_W4 + i] = (n < 600 && k < 200) ? f2bf(gw4[n * 200 + k]) : (ushort_t)0;
  }
}

__global__ void prep_fac(const float* __restrict__ fw, ushort_t* __restrict__ ws) {
  int n = blockIdx.x;   // 64 rows
  int l = threadIdx.x;  // 64 lanes
  float ss = 0.f;
  for (int k = l; k < 200; k += 64) { float v = fw[n * 200 + k]; ss = fmaf(v, v, ss); }
  for (int off = 32; off; off >>= 1) ss += __shfl_down(ss, off, 64);
  ss = __shfl(ss, 0, 64);
  float inv = 1.0f / fmaxf(sqrtf(ss), 1e-12f);
  for (int k = l; k < 224; k += 64)
    ws[WS_W5 + n * 224 + k] = (k < 200) ? f2bf(fw[n * 200 + k] * inv) : (ushort_t)0;
}

__global__ __launch_bounds__(NT, 4) void decoder_kernel(
    const float* __restrict__ x, const float* __restrict__ h0, const float* __restrict__ eps,
    const float* __restrict__ gen_b_ih, const float* __restrict__ gen_b_hh,
    const float* __restrict__ con_b_ih, const float* __restrict__ con_b_hh,
    const float* __restrict__ co_w, const float* __restrict__ co_b,
    const ushort_t* __restrict__ ws, float* __restrict__ out)
{
  __shared__ __align__(16) unsigned char spool[80896];
  ushort_t* sA  = (ushort_t*)spool;            // [64][328] con_input bf16
  ushort_t* sG  = (ushort_t*)spool;            // [64][232] gen_state bf16 (after con gi)
  ushort_t* sH  = (ushort_t*)(spool + 41984);  // [64][136] con_state bf16
  float*    sHn = (float*)(spool + 41984);     // [64][132] con_state_new f32 (after gh)
  ushort_t* sGn = (ushort_t*)(spool + 41984);  // [64][232] gen_state_new bf16 (after co)
  ushort_t* sGI = (ushort_t*)(spool + 75776);  // [64][40]  gen_input bf16

  const int tid = threadIdx.x;
  const int rbase = blockIdx.x * RT;
  const int lane = tid & 63;
  const int w = tid >> 6;
  const int bn = lane & 15;           // frag row/col within 16
  const int kq = (lane >> 4) << 3;    // k offset of quarter-wave
  const int qrow = (lane >> 4) << 2;  // C/D row offset of quarter-wave

  // ---------------- phase 1: stage con_input, con_state, factor; ext->out
  for (int idx = tid; idx < 64 * 68; idx += NT) {
    int r = idx / 68, c4 = (idx - r * 68) << 2;
    f4 v = *(const f4*)&x[(size_t)(rbase + r) * XD + c4];
    if (c4 < 256) {
      *(us4*)&sA[r * STA + c4] = f2bf4(v);
    } else {
      int e = c4 - 256;
      *(us4*)&sGI[r * STGI + 4 + e] = f2bf4(v);
      *(f4*)&out[(size_t)(rbase + r) * HD + 340 + e] = v;
    }
  }
  for (int idx = tid; idx < 64 * 32; idx += NT) {
    int r = idx >> 5, c4 = (idx & 31) << 2;
    f4 v = *(const f4*)&h0[(size_t)(rbase + r) * HD + 200 + c4];
    *(us4*)&sH[r * STH + c4] = f2bf4(v);
  }
  for (int idx = tid; idx < 64 * 16; idx += NT) {
    int r = idx >> 4, c4 = (idx & 15) << 2;
    f4 v = *(const f4*)&h0[(size_t)(rbase + r) * HD + 356 + c4];
    *(us4*)&sA[r * STA + 256 + c4] = f2bf4(v);
  }
  for (int idx = tid; idx < 64 * 3; idx += NT) {
    int r = idx / 3, q = (idx - r * 3) << 2;
    us4 z = {0, 0, 0, 0};
    *(us4*)&sGI[r * STGI + 20 + q] = z;
  }
  __syncthreads();

  const int col = (w << 4) + bn;  // this wave's output column (con phase: 0..127)

  // ---------------- phase 2a: con gh (K=128), accH for all 4 row-tiles
  f4 aH[3][4];
  #pragma unroll
  for (int g = 0; g < 3; ++g)
    #pragma unroll
    for (int ri = 0; ri < 4; ++ri) aH[g][ri] = (f4){0.f, 0.f, 0.f, 0.f};
  {
    const ushort_t* W2 = ws + WS_W2;
    #pragma unroll
    for (int k0 = 0; k0 < 128; k0 += 32) {
      bf8 b0 = *(const bf8*)&W2[(size_t)(col) * 128 + k0 + kq];
      bf8 b1 = *(const bf8*)&W2[(size_t)(128 + col) * 128 + k0 + kq];
      bf8 b2 = *(const bf8*)&W2[(size_t)(256 + col) * 128 + k0 + kq];
      #pragma unroll
      for (int ri = 0; ri < 4; ++ri) {
        bf8 a = *(const bf8*)&sH[(ri * 16 + bn) * STH + k0 + kq];
        aH[0][ri] = MFMA(a, b0, aH[0][ri]);
        aH[1][ri] = MFMA(a, b1, aH[1][ri]);
        aH[2][ri] = MFMA(a, b2, aH[2][ri]);
      }
    }
  }
  __syncthreads();  // sH dead; sHn (same region) may be written in 2b

  // ---------------- phase 2b: con gi (K=320) by ri-pairs + GRU elementwise
  {
    const ushort_t* W1 = ws + WS_W1;
    float bi0 = con_b_ih[col], bi1 = con_b_ih[128 + col], bi2 = con_b_ih[256 + col];
    float bh0 = con_b_hh[col], bh1 = con_b_hh[128 + col], bh2 = con_b_hh[256 + col];
    #pragma unroll
    for (int pr = 0; pr < 2; ++pr) {
      f4 aI[3][2];
      #pragma unroll
      for (int g = 0; g < 3; ++g)
        #pragma unroll
        for (int i = 0; i < 2; ++i) aI[g][i] = (f4){0.f, 0.f, 0.f, 0.f};
      #pragma unroll
      for (int k0 = 0; k0 < 320; k0 += 32) {
        bf8 b0 = *(const bf8*)&W1[(size_t)(col) * 320 + k0 + kq];
        bf8 b1 = *(const bf8*)&W1[(size_t)(128 + col) * 320 + k0 + kq];
        bf8 b2 = *(const bf8*)&W1[(size_t)(256 + col) * 320 + k0 + kq];
        #pragma unroll
        for (int i = 0; i < 2; ++i) {
          bf8 a = *(const bf8*)&sA[((2 * pr + i) * 16 + bn) * STA + k0 + kq];
          aI[0][i] = MFMA(a, b0, aI[0][i]);
          aI[1][i] = MFMA(a, b1, aI[1][i]);
          aI[2][i] = MFMA(a, b2, aI[2][i]);
        }
      }
      #pragma unroll
      for (int i = 0; i < 2; ++i) {
        int ri = 2 * pr + i;
        #pragma unroll
        for (int j = 0; j < 4; ++j) {
          int row = ri * 16 + qrow + j;
          size_t orow = (size_t)(rbase + row) * HD;
          float hold = h0[orow + 200 + col];
          float rr = sigf(aI[0][i][j] + bi0 + aH[0][ri][j] + bh0);
          float zz = sigf(aI[1][i][j] + bi1 + aH[1][ri][j] + bh1);
          float nn = tanhf_(aI[2][i][j] + bi2 + rr * (aH[2][ri][j] + bh2));
          float hv = (1.f - zz) * nn + zz * hold;
          hv = fminf(fmaxf(hv, -5.f), 5.f);
          out[orow + 200 + col] = hv;
          sHn[row * SHN + col] = hv;
        }
      }
    }
  }
  __syncthreads();

  // ---------------- phase 3: co linear + reparam (f32 VALU) ; stage gen_state
  {
    int crow = tid >> 3, cn = tid & 7;
    float acc = co_b[cn];
    #pragma unroll 8
    for (int k0 = 0; k0 < 128; k0 += 4) {
      f4 hv = *(const f4*)&sHn[crow * SHN + k0];
      f4 wv = *(const f4*)&co_w[cn * 128 + k0];
      acc = fmaf(hv.x, wv.x, acc);
      acc = fmaf(hv.y, wv.y, acc);
      acc = fmaf(hv.z, wv.z, acc);
      acc = fmaf(hv.w, wv.w, acc);
    }
    float lv = __shfl(acc, lane + 4, 64);  // partner lane holds logvar
    if (cn < 4) {
      float stdv = __expf(0.5f * lv);
      float ov = fmaf(stdv, eps[(size_t)(rbase + crow) * 4 + cn], acc);
      size_t orow = (size_t)(rbase + crow) * HD;
      out[orow + 328 + cn] = acc;
      out[orow + 332 + cn] = stdv;
      out[orow + 336 + cn] = ov;
      sGI[crow * STGI + cn] = f2bf(ov);
    }
  }
  for (int idx = tid; idx < 64 * 50; idx += NT) {
    int r = idx / 50, c4 = (idx - r * 50) << 2;
    f4 v = *(const f4*)&h0[(size_t)(rbase + r) * HD + c4];
    *(us4*)&sG[r * STG + c4] = f2bf4(v);
  }
  for (int idx = tid; idx < 64 * 6; idx += NT) {
    int r = idx / 6, q = (idx - r * 6) << 2;
    us4 z = {0, 0, 0, 0};
    *(us4*)&sG[r * STG + 200 + q] = z;
  }
  __syncthreads();

  // ---------------- phase 4: gen GRU (13 col-tiles over 8 waves)
  // zero sGn pad cols 200-223 (sHn dead past barrier; disjoint from sG/sGI)
  for (int idx = tid; idx < 64 * 6; idx += NT) {
    int r = idx / 6, q = (idx - r * 6) << 2;
    us4 z = {0, 0, 0, 0};
    *(us4*)&sGn[r * STG + 200 + q] = z;
  }
  {
    const ushort_t* W3 = ws + WS_W3;
    const ushort_t* W4 = ws + WS_W4;
    for (int t = w; t < 13; t += 8) {
      int c = (t << 4) + bn;  // output column 0..207 (valid < 200)
      float bi0 = 0.f, bi1 = 0.f, bi2 = 0.f, bh0 = 0.f, bh1 = 0.f, bh2 = 0.f;
      if (c < 200) {
        bi0 = gen_b_ih[c]; bi1 = gen_b_ih[200 + c]; bi2 = gen_b_ih[400 + c];
        bh0 = gen_b_hh[c]; bh1 = gen_b_hh[200 + c]; bh2 = gen_b_hh[400 + c];
      }
      #pragma unroll
      for (int pr = 0; pr < 2; ++pr) {
        f4 gI[3][2], gH[3][2];
        #pragma unroll
        for (int g = 0; g < 3; ++g)
          #pragma unroll
          for (int i = 0; i < 2; ++i) {
            gI[g][i] = (f4){0.f, 0.f, 0.f, 0.f};
            gH[g][i] = (f4){0.f, 0.f, 0.f, 0.f};
          }
        {
          bf8 b0 = *(const bf8*)&W3[(size_t)(c) * 32 + kq];
          bf8 b1 = *(const bf8*)&W3[(size_t)(200 + c) * 32 + kq];
          bf8 b2 = *(const bf8*)&W3[(size_t)(400 + c) * 32 + kq];
          #pragma unroll
          for (int i = 0; i < 2; ++i) {
            bf8 a = *(const bf8*)&sGI[((2 * pr + i) * 16 + bn) * STGI + kq];
            gI[0][i] = MFMA(a, b0, gI[0][i]);
            gI[1][i] = MFMA(a, b1, gI[1][i]);
            gI[2][i] = MFMA(a, b2, gI[2][i]);
          }
        }
        #pragma unroll
        for (int k0 = 0; k0 < 224; k0 += 32) {
          bf8 b0 = *(const bf8*)&W4[(size_t)(c) * 224 + k0 + kq];
          bf8 b1 = *(const bf8*)&W4[(size_t)(200 + c) * 224 + k0 + kq];
          bf8 b2 = *(const bf8*)&W4[(size_t)(400 + c) * 224 + k0 + kq];
          #pragma unroll
          for (int i = 0; i < 2; ++i) {
            bf8 a = *(const bf8*)&sG[((2 * pr + i) * 16 + bn) * STG + k0 + kq];
            gH[0][i] = MFMA(a, b0, gH[0][i]);
            gH[1][i] = MFMA(a, b1, gH[1][i]);
            gH[2][i] = MFMA(a, b2, gH[2][i]);
          }
        }
        if (c < 200) {
          #pragma unroll
          for (int i = 0; i < 2; ++i) {
            #pragma unroll
            for (int j = 0; j < 4; ++j) {
              int row = (2 * pr + i) * 16 + qrow + j;
              size_t orow = (size_t)(rbase + row) * HD;
              float hold = h0[orow + c];
              float rr = sigf(gI[0][i][j] + bi0 + gH[0][i][j] + bh0);
              float zz = sigf(gI[1][i][j] + bi1 + gH[1][i][j] + bh1);
              float nn = tanhf_(gI[2][i][j] + bi2 + rr * (gH[2][i][j] + bh2));
              float hv = (1.f - zz) * nn + zz * hold;
              hv = fminf(fmaxf(hv, -5.f), 5.f);
              out[orow + c] = hv;
              sGn[row * STG + c] = f2bf(hv);
            }
          }
        }
      }
    }
  }
  __syncthreads();

  // ---------------- phase 5: factor = gen_state_new @ normed_fac^T (64 cols)
  {
    const ushort_t* W5 = ws + WS_W5;
    int ri = w & 3;
    #pragma unroll
    for (int cc = 0; cc < 2; ++cc) {
      int ct = (w >> 2) + cc * 2;  // 0..3
      f4 acc = (f4){0.f, 0.f, 0.f, 0.f};
      #pragma unroll
      for (int k0 = 0; k0 < 224; k0 += 32) {
        bf8 b = *(const bf8*)&W5[(size_t)((ct << 4) + bn) * 224 + k0 + kq];
        bf8 a = *(const bf8*)&sGn[(ri * 16 + bn) * STG + k0 + kq];
        acc = MFMA(a, b, acc);
      }
      #pragma unroll
      for (int j = 0; j < 4; ++j) {
        int row = ri * 16 + qrow + j;
        out[(size_t)(rbase + row) * HD + 356 + (ct << 4) + bn] = acc[j];
      }
    }
  }
}

extern "C" void kernel_launch(void* const* d_in, const int* in_sizes, int n_in,
                              void* d_out, int out_size, void* d_ws, size_t ws_size,
                              hipStream_t stream) {
  const float* x        = (const float*)d_in[0];
  const float* h0       = (const float*)d_in[1];
  const float* eps      = (const float*)d_in[2];
  const float* gen_w_ih = (const float*)d_in[3];
  const float* gen_w_hh = (const float*)d_in[4];
  const float* gen_b_ih = (const float*)d_in[5];
  const float* gen_b_hh = (const float*)d_in[6];
  const float* con_w_ih = (const float*)d_in[7];
  const float* con_w_hh = (const float*)d_in[8];
  const float* con_b_ih = (const float*)d_in[9];
  const float* con_b_hh = (const float*)d_in[10];
  const float* co_w     = (const float*)d_in[11];
  const float* co_b     = (const float*)d_in[12];
  const float* fac_w    = (const float*)d_in[13];
  float* out = (float*)d_out;
  ushort_t* ws = (ushort_t*)d_ws;

  hipLaunchKernelGGL(prep_w, dim3(256), dim3(512), 0, stream,
                     con_w_ih, con_w_hh, gen_w_ih, gen_w_hh, ws);
  hipLaunchKernelGGL(prep_fac, dim3(64), dim3(64), 0, stream, fac_w, ws);

  int nrows = in_sizes[2] / 4;  // eps is (B,4)
  int grid = nrows / RT;        // 1024
  hipLaunchKernelGGL(decoder_kernel, dim3(grid), dim3(NT), 0, stream,
                     x, h0, eps, gen_b_ih, gen_b_hh, con_b_ih, con_b_hh,
                     co_w, co_b, ws, out);
}

// Round 3
// 238.847 us; speedup vs baseline: 5.6011x; 1.3811x over previous
//
#include <hip/hip_runtime.h>
#include <math.h>

// DecoderCell fused kernel — Round 3: bf16 MFMA + full LDS out-tile with one
// coalesced flush. All GRU holds read from staged LDS (no h0 re-reads); the
// factor GEMM reads its A operand (gen_state_new) straight out of the bf16
// out-tile. Single 107,520B contiguous f32 stream store per block.

#define NT 512
#define RT 64
#define XD 272
#define HD 420

typedef unsigned short ushort_t;
typedef __attribute__((ext_vector_type(8))) short bf8;
typedef __attribute__((ext_vector_type(4))) float f4;
typedef __attribute__((ext_vector_type(4))) unsigned short us4;

// ws layout (bf16 element offsets)
#define WS_W1 0         // con_w_ih [384][320]
#define WS_W2 122880    // con_w_hh [384][128]
#define WS_W3 172032    // gen_w_ih [608][32]  (K 20->32 pad, rows 600-607 zero)
#define WS_W4 191488    // gen_w_hh [608][224] (K 200->224 pad, rows 600-607 zero)
#define WS_W5 327680    // normed fac_w [64][224] (K pad zero)

// LDS strides (bf16 elements); all give 16-row frag reads <=2-way banked
#define SOB 424   // out tile [64][424] (cols 0..419 used)
#define STA 328   // con_input [64][328]
#define STG 232   // gen_state_old [64][232] (aliases sA region)
#define STH 136   // con_state_old [64][136]
#define STGI 40   // gen_input [64][40]

// byte offsets in pool
#define O_OUT 0        // 54,272
#define O_AG  54272    // 41,984 (sA) / 29,696 (sG)
#define O_H   96256    // 17,408
#define O_GI  113664   // 5,120
#define POOLB 118784

__device__ __forceinline__ ushort_t f2bf(float f) {
  union { float f; unsigned u; } v; v.f = f;
  unsigned r = v.u + 0x7FFFu + ((v.u >> 16) & 1u);
  return (ushort_t)(r >> 16);
}
__device__ __forceinline__ float bf2f(ushort_t u) {
  union { unsigned u; float f; } v; v.u = ((unsigned)u) << 16; return v.f;
}
__device__ __forceinline__ us4 f2bf4(f4 v) {
  us4 b; b.x = f2bf(v.x); b.y = f2bf(v.y); b.z = f2bf(v.z); b.w = f2bf(v.w); return b;
}
__device__ __forceinline__ f4 bf2f4(us4 b) {
  f4 v; v.x = bf2f(b.x); v.y = bf2f(b.y); v.z = bf2f(b.z); v.w = bf2f(b.w); return v;
}
__device__ __forceinline__ float sigf(float x) { return 1.0f / (1.0f + __expf(-x)); }
__device__ __forceinline__ float tanhf_(float x) { float e = __expf(2.0f * x); return 1.0f - 2.0f / (e + 1.0f); }

#define MFMA(a, b, c) __builtin_amdgcn_mfma_f32_16x16x32_bf16((a), (b), (c), 0, 0, 0)

__global__ void prep_w(const float* __restrict__ cw1, const float* __restrict__ cw2,
                       const float* __restrict__ gw3, const float* __restrict__ gw4,
                       ushort_t* __restrict__ ws) {
  int tid = blockIdx.x * blockDim.x + threadIdx.x;
  int np = gridDim.x * blockDim.x;
  for (int i = tid; i < 384 * 320; i += np) ws[WS_W1 + i] = f2bf(cw1[i]);
  for (int i = tid; i < 384 * 128; i += np) ws[WS_W2 + i] = f2bf(cw2[i]);
  for (int i = tid; i < 608 * 32; i += np) {
    int n = i >> 5, k = i & 31;
    ws[WS_W3 + i] = (n < 600 && k < 20) ? f2bf(gw3[n * 20 + k]) : (ushort_t)0;
  }
  for (int i = tid; i < 608 * 224; i += np) {
    int n = i / 224, k = i - n * 224;
    ws[WS_W4 + i] = (n < 600 && k < 200) ? f2bf(gw4[n * 200 + k]) : (ushort_t)0;
  }
}

__global__ void prep_fac(const float* __restrict__ fw, ushort_t* __restrict__ ws) {
  int n = blockIdx.x;   // 64 rows
  int l = threadIdx.x;  // 64 lanes
  float ss = 0.f;
  for (int k = l; k < 200; k += 64) { float v = fw[n * 200 + k]; ss = fmaf(v, v, ss); }
  for (int off = 32; off; off >>= 1) ss += __shfl_down(ss, off, 64);
  ss = __shfl(ss, 0, 64);
  float inv = 1.0f / fmaxf(sqrtf(ss), 1e-12f);
  for (int k = l; k < 224; k += 64)
    ws[WS_W5 + n * 224 + k] = (k < 200) ? f2bf(fw[n * 200 + k] * inv) : (ushort_t)0;
}

__global__ __launch_bounds__(NT, 2) void decoder_kernel(
    const float* __restrict__ x, const float* __restrict__ h0, const float* __restrict__ eps,
    const float* __restrict__ gen_b_ih, const float* __restrict__ gen_b_hh,
    const float* __restrict__ con_b_ih, const float* __restrict__ con_b_hh,
    const float* __restrict__ co_w, const float* __restrict__ co_b,
    const ushort_t* __restrict__ ws, float* __restrict__ out)
{
  __shared__ __align__(16) unsigned char spool[POOLB];
  ushort_t* sOut = (ushort_t*)(spool + O_OUT);  // [64][424] full out tile bf16
  ushort_t* sA   = (ushort_t*)(spool + O_AG);   // [64][328] con_input
  ushort_t* sG   = (ushort_t*)(spool + O_AG);   // [64][232] gen_state_old (after ph2b)
  ushort_t* sH   = (ushort_t*)(spool + O_H);    // [64][136] con_state_old
  ushort_t* sGI  = (ushort_t*)(spool + O_GI);   // [64][40]  gen_input

  const int tid = threadIdx.x;
  const int rbase = blockIdx.x * RT;
  const int lane = tid & 63;
  const int w = tid >> 6;
  const int bn = lane & 15;           // frag row/col within 16
  const int kq = (lane >> 4) << 3;    // k offset of quarter-wave
  const int qrow = (lane >> 4) << 2;  // C/D row offset of quarter-wave

  // ---------------- phase 1: stage con_input, con_state, factor; ext
  #pragma unroll
  for (int it = 0; it < 8; ++it) {  // x[:,0:256] -> sA
    int idx = tid + it * NT;
    int r = idx >> 6, c4 = (idx & 63) << 2;
    f4 v = *(const f4*)&x[(size_t)(rbase + r) * XD + c4];
    *(us4*)&sA[r * STA + c4] = f2bf4(v);
  }
  if (tid < 256) {  // x[:,256:272] -> sGI cols 4..20 and out cols 340..356
    int r = tid >> 2, e = (tid & 3) << 2;
    f4 v = *(const f4*)&x[(size_t)(rbase + r) * XD + 256 + e];
    us4 b = f2bf4(v);
    *(us4*)&sGI[r * STGI + 4 + e] = b;
    *(us4*)&sOut[r * SOB + 340 + e] = b;
  }
  #pragma unroll
  for (int it = 0; it < 4; ++it) {  // h0[:,200:328] -> sH
    int idx = tid + it * NT;
    int r = idx >> 5, c4 = (idx & 31) << 2;
    f4 v = *(const f4*)&h0[(size_t)(rbase + r) * HD + 200 + c4];
    *(us4*)&sH[r * STH + c4] = f2bf4(v);
  }
  #pragma unroll
  for (int it = 0; it < 2; ++it) {  // h0[:,356:420] -> sA cols 256..320
    int idx = tid + it * NT;
    int r = idx >> 4, c4 = (idx & 15) << 2;
    f4 v = *(const f4*)&h0[(size_t)(rbase + r) * HD + 356 + c4];
    *(us4*)&sA[r * STA + 256 + c4] = f2bf4(v);
  }
  if (tid < 192) {  // zero sGI cols 20..32 (frag K-pad)
    int r = tid / 3, q = (tid - (tid / 3) * 3) << 2;
    us4 z = {0, 0, 0, 0};
    *(us4*)&sGI[r * STGI + 20 + q] = z;
  }
  __syncthreads();

  const int col = (w << 4) + bn;  // wave's output column (con phase: 0..127)

  // ---------------- phase 2a: con gh (K=128), accH for all 4 row-tiles
  f4 aH[3][4];
  #pragma unroll
  for (int g = 0; g < 3; ++g)
    #pragma unroll
    for (int ri = 0; ri < 4; ++ri) aH[g][ri] = (f4){0.f, 0.f, 0.f, 0.f};
  {
    const ushort_t* W2 = ws + WS_W2;
    #pragma unroll
    for (int k0 = 0; k0 < 128; k0 += 32) {
      bf8 b0 = *(const bf8*)&W2[(size_t)(col) * 128 + k0 + kq];
      bf8 b1 = *(const bf8*)&W2[(size_t)(128 + col) * 128 + k0 + kq];
      bf8 b2 = *(const bf8*)&W2[(size_t)(256 + col) * 128 + k0 + kq];
      #pragma unroll
      for (int ri = 0; ri < 4; ++ri) {
        bf8 a = *(const bf8*)&sH[(ri * 16 + bn) * STH + k0 + kq];
        aH[0][ri] = MFMA(a, b0, aH[0][ri]);
        aH[1][ri] = MFMA(a, b1, aH[1][ri]);
        aH[2][ri] = MFMA(a, b2, aH[2][ri]);
      }
    }
  }

  // ---------------- phase 2b: con gi (K=320) by ri-pairs + GRU elementwise
  {
    const ushort_t* W1 = ws + WS_W1;
    float bi0 = con_b_ih[col], bi1 = con_b_ih[128 + col], bi2 = con_b_ih[256 + col];
    float bh0 = con_b_hh[col], bh1 = con_b_hh[128 + col], bh2 = con_b_hh[256 + col];
    #pragma unroll
    for (int pr = 0; pr < 2; ++pr) {
      f4 aI[3][2];
      #pragma unroll
      for (int g = 0; g < 3; ++g)
        #pragma unroll
        for (int i = 0; i < 2; ++i) aI[g][i] = (f4){0.f, 0.f, 0.f, 0.f};
      #pragma unroll
      for (int k0 = 0; k0 < 320; k0 += 32) {
        bf8 b0 = *(const bf8*)&W1[(size_t)(col) * 320 + k0 + kq];
        bf8 b1 = *(const bf8*)&W1[(size_t)(128 + col) * 320 + k0 + kq];
        bf8 b2 = *(const bf8*)&W1[(size_t)(256 + col) * 320 + k0 + kq];
        #pragma unroll
        for (int i = 0; i < 2; ++i) {
          bf8 a = *(const bf8*)&sA[((2 * pr + i) * 16 + bn) * STA + k0 + kq];
          aI[0][i] = MFMA(a, b0, aI[0][i]);
          aI[1][i] = MFMA(a, b1, aI[1][i]);
          aI[2][i] = MFMA(a, b2, aI[2][i]);
        }
      }
      #pragma unroll
      for (int i = 0; i < 2; ++i) {
        int ri = 2 * pr + i;
        #pragma unroll
        for (int j = 0; j < 4; ++j) {
          int row = ri * 16 + qrow + j;
          float hold = bf2f(sH[row * STH + col]);
          float rr = sigf(aI[0][i][j] + bi0 + aH[0][ri][j] + bh0);
          float zz = sigf(aI[1][i][j] + bi1 + aH[1][ri][j] + bh1);
          float nn = tanhf_(aI[2][i][j] + bi2 + rr * (aH[2][ri][j] + bh2));
          float hv = (1.f - zz) * nn + zz * hold;
          hv = fminf(fmaxf(hv, -5.f), 5.f);
          sOut[row * SOB + 200 + col] = f2bf(hv);
        }
      }
    }
  }
  __syncthreads();

  // ---------------- phase 3: co linear + reparam (f32 VALU) ; stage gen_state
  {
    int crow = tid >> 3, cn = tid & 7;
    float acc = co_b[cn];
    #pragma unroll 8
    for (int k0 = 0; k0 < 128; k0 += 4) {
      f4 hv = bf2f4(*(const us4*)&sOut[crow * SOB + 200 + k0]);
      f4 wv = *(const f4*)&co_w[cn * 128 + k0];
      acc = fmaf(hv.x, wv.x, acc);
      acc = fmaf(hv.y, wv.y, acc);
      acc = fmaf(hv.z, wv.z, acc);
      acc = fmaf(hv.w, wv.w, acc);
    }
    float lv = __shfl(acc, lane + 4, 64);  // partner lane holds logvar
    if (cn < 4) {
      float stdv = __expf(0.5f * lv);
      float ov = fmaf(stdv, eps[(size_t)(rbase + crow) * 4 + cn], acc);
      sOut[crow * SOB + 328 + cn] = f2bf(acc);
      sOut[crow * SOB + 332 + cn] = f2bf(stdv);
      sOut[crow * SOB + 336 + cn] = f2bf(ov);
      sGI[crow * STGI + cn] = f2bf(ov);
    }
  }
  for (int idx = tid; idx < 64 * 50; idx += NT) {  // h0[:,0:200] -> sG
    int r = idx / 50, c4 = (idx - (idx / 50) * 50) << 2;
    f4 v = *(const f4*)&h0[(size_t)(rbase + r) * HD + c4];
    *(us4*)&sG[r * STG + c4] = f2bf4(v);
  }
  if (tid < 384) {  // zero sG cols 200..224 (frag K-pad)
    int r = tid / 6, q = (tid - (tid / 6) * 6) << 2;
    us4 z = {0, 0, 0, 0};
    *(us4*)&sG[r * STG + 200 + q] = z;
  }
  __syncthreads();

  // ---------------- phase 4: gen GRU (13 col-tiles over 8 waves)
  {
    const ushort_t* W3 = ws + WS_W3;
    const ushort_t* W4 = ws + WS_W4;
    for (int t = w; t < 13; t += 8) {
      int c = (t << 4) + bn;  // output column 0..207 (valid < 200)
      float bi0 = 0.f, bi1 = 0.f, bi2 = 0.f, bh0 = 0.f, bh1 = 0.f, bh2 = 0.f;
      if (c < 200) {
        bi0 = gen_b_ih[c]; bi1 = gen_b_ih[200 + c]; bi2 = gen_b_ih[400 + c];
        bh0 = gen_b_hh[c]; bh1 = gen_b_hh[200 + c]; bh2 = gen_b_hh[400 + c];
      }
      #pragma unroll
      for (int pr = 0; pr < 2; ++pr) {
        f4 gI[3][2], gH[3][2];
        #pragma unroll
        for (int g = 0; g < 3; ++g)
          #pragma unroll
          for (int i = 0; i < 2; ++i) {
            gI[g][i] = (f4){0.f, 0.f, 0.f, 0.f};
            gH[g][i] = (f4){0.f, 0.f, 0.f, 0.f};
          }
        {
          bf8 b0 = *(const bf8*)&W3[(size_t)(c) * 32 + kq];
          bf8 b1 = *(const bf8*)&W3[(size_t)(200 + c) * 32 + kq];
          bf8 b2 = *(const bf8*)&W3[(size_t)(400 + c) * 32 + kq];
          #pragma unroll
          for (int i = 0; i < 2; ++i) {
            bf8 a = *(const bf8*)&sGI[((2 * pr + i) * 16 + bn) * STGI + kq];
            gI[0][i] = MFMA(a, b0, gI[0][i]);
            gI[1][i] = MFMA(a, b1, gI[1][i]);
            gI[2][i] = MFMA(a, b2, gI[2][i]);
          }
        }
        #pragma unroll
        for (int k0 = 0; k0 < 224; k0 += 32) {
          bf8 b0 = *(const bf8*)&W4[(size_t)(c) * 224 + k0 + kq];
          bf8 b1 = *(const bf8*)&W4[(size_t)(200 + c) * 224 + k0 + kq];
          bf8 b2 = *(const bf8*)&W4[(size_t)(400 + c) * 224 + k0 + kq];
          #pragma unroll
          for (int i = 0; i < 2; ++i) {
            bf8 a = *(const bf8*)&sG[((2 * pr + i) * 16 + bn) * STG + k0 + kq];
            gH[0][i] = MFMA(a, b0, gH[0][i]);
            gH[1][i] = MFMA(a, b1, gH[1][i]);
            gH[2][i] = MFMA(a, b2, gH[2][i]);
          }
        }
        if (c < 200) {
          #pragma unroll
          for (int i = 0; i < 2; ++i) {
            #pragma unroll
            for (int j = 0; j < 4; ++j) {
              int row = (2 * pr + i) * 16 + qrow + j;
              float hold = bf2f(sG[row * STG + c]);
              float rr = sigf(gI[0][i][j] + bi0 + gH[0][i][j] + bh0);
              float zz = sigf(gI[1][i][j] + bi1 + gH[1][i][j] + bh1);
              float nn = tanhf_(gI[2][i][j] + bi2 + rr * (gH[2][i][j] + bh2));
              float hv = (1.f - zz) * nn + zz * hold;
              hv = fminf(fmaxf(hv, -5.f), 5.f);
              sOut[row * SOB + c] = f2bf(hv);
            }
          }
        }
      }
    }
  }
  __syncthreads();

  // ---------------- phase 5: factor = gen_state_new @ normed_fac^T (64 cols)
  {
    const ushort_t* W5 = ws + WS_W5;
    int ri = w & 3;
    #pragma unroll
    for (int cc = 0; cc < 2; ++cc) {
      int ct = (w >> 2) + cc * 2;  // 0..3
      f4 acc = (f4){0.f, 0.f, 0.f, 0.f};
      #pragma unroll
      for (int k0 = 0; k0 < 224; k0 += 32) {
        bf8 b = *(const bf8*)&W5[(size_t)((ct << 4) + bn) * 224 + k0 + kq];
        bf8 a = *(const bf8*)&sOut[(ri * 16 + bn) * SOB + k0 + kq];
        acc = MFMA(a, b, acc);
      }
      #pragma unroll
      for (int j = 0; j < 4; ++j) {
        int row = ri * 16 + qrow + j;
        sOut[row * SOB + 356 + (ct << 4) + bn] = f2bf(acc[j]);
      }
    }
  }
  __syncthreads();

  // ---------------- phase 6: coalesced flush (contiguous 107,520 B span)
  for (int idx = tid; idx < 64 * 105; idx += NT) {
    int r = idx / 105, c = (idx - (idx / 105) * 105) << 2;
    f4 v = bf2f4(*(const us4*)&sOut[r * SOB + c]);
    *(f4*)&out[(size_t)(rbase + r) * HD + c] = v;
  }
}

extern "C" void kernel_launch(void* const* d_in, const int* in_sizes, int n_in,
                              void* d_out, int out_size, void* d_ws, size_t ws_size,
                              hipStream_t stream) {
  const float* x        = (const float*)d_in[0];
  const float* h0       = (const float*)d_in[1];
  const float* eps      = (const float*)d_in[2];
  const float* gen_w_ih = (const float*)d_in[3];
  const float* gen_w_hh = (const float*)d_in[4];
  const float* gen_b_ih = (const float*)d_in[5];
  const float* gen_b_hh = (const float*)d_in[6];
  const float* con_w_ih = (const float*)d_in[7];
  const float* con_w_hh = (const float*)d_in[8];
  const float* con_b_ih = (const float*)d_in[9];
  const float* con_b_hh = (const float*)d_in[10];
  const float* co_w     = (const float*)d_in[11];
  const float* co_b     = (const float*)d_in[12];
  const float* fac_w    = (const float*)d_in[13];
  float* out = (float*)d_out;
  ushort_t* ws = (ushort_t*)d_ws;

  hipLaunchKernelGGL(prep_w, dim3(256), dim3(512), 0, stream,
                     con_w_ih, con_w_hh, gen_w_ih, gen_w_hh, ws);
  hipLaunchKernelGGL(prep_fac, dim3(64), dim3(64), 0, stream, fac_w, ws);

  int nrows = in_sizes[2] / 4;  // eps is (B,4)
  int grid = nrows / RT;        // 1024
  hipLaunchKernelGGL(decoder_kernel, dim3(grid), dim3(NT), 0, stream,
                     x, h0, eps, gen_b_ih, gen_b_hh, con_b_ih, con_b_hh,
                     co_w, co_b, ws, out);
}

// Round 4
// 207.803 us; speedup vs baseline: 6.4378x; 1.1494x over previous
//
#include <hip/hip_runtime.h>
#include <math.h>

// DecoderCell fused kernel — Round 4: 2 blocks/CU (80.9 KB LDS via region
// aliasing + 3-span flush) and single-pass weight reads (k0-outer, merged
// r/z accumulators: r,z gates are sig(i+h) so gi and gh share one acc; only
// the n gate keeps separate i/h accs). All GEMMs bf16 MFMA 16x16x32.
//
// LDS pool (bytes):
//   [0,41984)      sA [64][328]   con_input       (ph1..conGEMM)
//                  sGo [64][216]  gen_state_old   (staged after conGEMM)
//   [41984,59392)  sR2 [64][136]  con_state (in-place new) + co mean/std
//   [41984,69632)  sGn [64][216]  gen_state_new   (after sR2 flushed)
//   [69632,80896)  sR3 [64][88]   gen_input(20) + factor(64) -> out[336:420)
// Stride-216 G tiles: k0=192 frag reads span cols 192..224 -> past-stride
// bytes hit next row / next region (finite bf16), multiplied by ws zero-pads.

#define NT 512
#define RT 64
#define XD 272
#define HD 420

typedef unsigned short ushort_t;
typedef __attribute__((ext_vector_type(8))) short bf8;
typedef __attribute__((ext_vector_type(4))) float f4;
typedef __attribute__((ext_vector_type(4))) unsigned short us4;

// ws layout (bf16 element offsets)
#define WS_W1 0         // con_w_ih [384][320]
#define WS_W2 122880    // con_w_hh [384][128]
#define WS_W3 172032    // gen_w_ih [608][32]  (K 20->32 pad, rows 600-607 zero)
#define WS_W4 191488    // gen_w_hh [608][224] (K 200->224 pad, rows 600-607 zero)
#define WS_W5 327680    // normed fac_w [64][224] (K pad zero)

#define STA 328
#define STG 216
#define STH 136
#define STR3 88

#define O_A   0
#define O_R2  41984
#define O_GN  41984
#define O_R3  69632
#define POOLB 80896

__device__ __forceinline__ ushort_t f2bf(float f) {
  union { float f; unsigned u; } v; v.f = f;
  unsigned r = v.u + 0x7FFFu + ((v.u >> 16) & 1u);
  return (ushort_t)(r >> 16);
}
__device__ __forceinline__ float bf2f(ushort_t u) {
  union { unsigned u; float f; } v; v.u = ((unsigned)u) << 16; return v.f;
}
__device__ __forceinline__ us4 f2bf4(f4 v) {
  us4 b; b.x = f2bf(v.x); b.y = f2bf(v.y); b.z = f2bf(v.z); b.w = f2bf(v.w); return b;
}
__device__ __forceinline__ f4 bf2f4(us4 b) {
  f4 v; v.x = bf2f(b.x); v.y = bf2f(b.y); v.z = bf2f(b.z); v.w = bf2f(b.w); return v;
}
__device__ __forceinline__ float sigf(float x) { return 1.0f / (1.0f + __expf(-x)); }
__device__ __forceinline__ float tanhf_(float x) { float e = __expf(2.0f * x); return 1.0f - 2.0f / (e + 1.0f); }

#define MFMA(a, b, c) __builtin_amdgcn_mfma_f32_16x16x32_bf16((a), (b), (c), 0, 0, 0)

__global__ void prep_w(const float* __restrict__ cw1, const float* __restrict__ cw2,
                       const float* __restrict__ gw3, const float* __restrict__ gw4,
                       ushort_t* __restrict__ ws) {
  int tid = blockIdx.x * blockDim.x + threadIdx.x;
  int np = gridDim.x * blockDim.x;
  for (int i = tid; i < 384 * 320; i += np) ws[WS_W1 + i] = f2bf(cw1[i]);
  for (int i = tid; i < 384 * 128; i += np) ws[WS_W2 + i] = f2bf(cw2[i]);
  for (int i = tid; i < 608 * 32; i += np) {
    int n = i >> 5, k = i & 31;
    ws[WS_W3 + i] = (n < 600 && k < 20) ? f2bf(gw3[n * 20 + k]) : (ushort_t)0;
  }
  for (int i = tid; i < 608 * 224; i += np) {
    int n = i / 224, k = i - n * 224;
    ws[WS_W4 + i] = (n < 600 && k < 200) ? f2bf(gw4[n * 200 + k]) : (ushort_t)0;
  }
}

__global__ void prep_fac(const float* __restrict__ fw, ushort_t* __restrict__ ws) {
  int n = blockIdx.x;   // 64 rows
  int l = threadIdx.x;  // 64 lanes
  float ss = 0.f;
  for (int k = l; k < 200; k += 64) { float v = fw[n * 200 + k]; ss = fmaf(v, v, ss); }
  for (int off = 32; off; off >>= 1) ss += __shfl_down(ss, off, 64);
  ss = __shfl(ss, 0, 64);
  float inv = 1.0f / fmaxf(sqrtf(ss), 1e-12f);
  for (int k = l; k < 224; k += 64)
    ws[WS_W5 + n * 224 + k] = (k < 200) ? f2bf(fw[n * 200 + k] * inv) : (ushort_t)0;
}

__global__ __launch_bounds__(NT, 2) void decoder_kernel(
    const float* __restrict__ x, const float* __restrict__ h0, const float* __restrict__ eps,
    const float* __restrict__ gen_b_ih, const float* __restrict__ gen_b_hh,
    const float* __restrict__ con_b_ih, const float* __restrict__ con_b_hh,
    const float* __restrict__ co_w, const float* __restrict__ co_b,
    const ushort_t* __restrict__ ws, float* __restrict__ out)
{
  __shared__ __align__(16) unsigned char spool[POOLB];
  ushort_t* sA  = (ushort_t*)(spool + O_A);    // con_input [64][328]
  ushort_t* sGo = (ushort_t*)(spool + O_A);    // gen_state_old [64][216]
  ushort_t* sR2 = (ushort_t*)(spool + O_R2);   // con_state(128)+mean(4)+std(4)
  ushort_t* sGn = (ushort_t*)(spool + O_GN);   // gen_state_new [64][216]
  ushort_t* sR3 = (ushort_t*)(spool + O_R3);   // gen_input(20)+factor(64) [64][88]

  const int tid = threadIdx.x;
  const int rbase = blockIdx.x * RT;
  const int lane = tid & 63;
  const int w = tid >> 6;
  const int bn = lane & 15;           // frag row/col within 16
  const int kq = (lane >> 4) << 3;    // k offset of quarter-wave
  const int qrow = (lane >> 4) << 2;  // C/D row offset of quarter-wave

  // ---------------- ph1: stage con_input, con_state, ext; zero gi pad
  #pragma unroll
  for (int it = 0; it < 8; ++it) {  // x[:,0:256] -> sA
    int idx = tid + it * NT;
    int r = idx >> 6, c4 = (idx & 63) << 2;
    f4 v = *(const f4*)&x[(size_t)(rbase + r) * XD + c4];
    *(us4*)&sA[r * STA + c4] = f2bf4(v);
  }
  if (tid < 256) {  // x[:,256:272] -> sR3 cols 4..20 (gen_input ext)
    int r = tid >> 2, e = (tid & 3) << 2;
    f4 v = *(const f4*)&x[(size_t)(rbase + r) * XD + 256 + e];
    *(us4*)&sR3[r * STR3 + 4 + e] = f2bf4(v);
  }
  #pragma unroll
  for (int it = 0; it < 4; ++it) {  // h0[:,200:328] -> sR2 (con_state_old)
    int idx = tid + it * NT;
    int r = idx >> 5, c4 = (idx & 31) << 2;
    f4 v = *(const f4*)&h0[(size_t)(rbase + r) * HD + 200 + c4];
    *(us4*)&sR2[r * STH + c4] = f2bf4(v);
  }
  #pragma unroll
  for (int it = 0; it < 2; ++it) {  // h0[:,356:420] -> sA cols 256..320
    int idx = tid + it * NT;
    int r = idx >> 4, c4 = (idx & 15) << 2;
    f4 v = *(const f4*)&h0[(size_t)(rbase + r) * HD + 356 + c4];
    *(us4*)&sA[r * STA + 256 + c4] = f2bf4(v);
  }
  if (tid < 192) {  // zero sR3 cols 20..32 (gi K-pad)
    int r = tid / 3, q = (tid - (tid / 3) * 3) << 2;
    us4 z = {0, 0, 0, 0};
    *(us4*)&sR3[r * STR3 + 20 + q] = z;
  }
  __syncthreads();  // B1

  const int col = (w << 4) + bn;  // wave's con output column (0..127)

  // ---------------- ph2: con GEMMs, single weight pass, merged r/z accs
  f4 aRZ[2][4], aN[4], aHN[4];
  #pragma unroll
  for (int ri = 0; ri < 4; ++ri) {
    aRZ[0][ri] = (f4){0.f, 0.f, 0.f, 0.f};
    aRZ[1][ri] = (f4){0.f, 0.f, 0.f, 0.f};
    aN[ri] = (f4){0.f, 0.f, 0.f, 0.f};
    aHN[ri] = (f4){0.f, 0.f, 0.f, 0.f};
  }
  {
    const ushort_t* W2 = ws + WS_W2;
    #pragma unroll
    for (int k0 = 0; k0 < 128; k0 += 32) {
      bf8 br = *(const bf8*)&W2[(size_t)(col) * 128 + k0 + kq];
      bf8 bz = *(const bf8*)&W2[(size_t)(128 + col) * 128 + k0 + kq];
      bf8 bm = *(const bf8*)&W2[(size_t)(256 + col) * 128 + k0 + kq];
      #pragma unroll
      for (int ri = 0; ri < 4; ++ri) {
        bf8 a = *(const bf8*)&sR2[(ri * 16 + bn) * STH + k0 + kq];
        aRZ[0][ri] = MFMA(a, br, aRZ[0][ri]);
        aRZ[1][ri] = MFMA(a, bz, aRZ[1][ri]);
        aHN[ri] = MFMA(a, bm, aHN[ri]);
      }
    }
    const ushort_t* W1 = ws + WS_W1;
    #pragma unroll
    for (int k0 = 0; k0 < 320; k0 += 32) {
      bf8 br = *(const bf8*)&W1[(size_t)(col) * 320 + k0 + kq];
      bf8 bz = *(const bf8*)&W1[(size_t)(128 + col) * 320 + k0 + kq];
      bf8 bm = *(const bf8*)&W1[(size_t)(256 + col) * 320 + k0 + kq];
      #pragma unroll
      for (int ri = 0; ri < 4; ++ri) {
        bf8 a = *(const bf8*)&sA[(ri * 16 + bn) * STA + k0 + kq];
        aRZ[0][ri] = MFMA(a, br, aRZ[0][ri]);
        aRZ[1][ri] = MFMA(a, bz, aRZ[1][ri]);
        aN[ri] = MFMA(a, bm, aN[ri]);
      }
    }
  }
  __syncthreads();  // B2 (sA dead; sR2 frag-reads done -> in-place update ok)

  // ---------------- ph3: stage gen_state_old (sA region) || con elementwise
  for (int idx = tid; idx < 64 * 54; idx += NT) {
    int r = idx / 54, u = idx - (idx / 54) * 54;
    if (u < 50) {
      f4 v = *(const f4*)&h0[(size_t)(rbase + r) * HD + (u << 2)];
      *(us4*)&sGo[r * STG + (u << 2)] = f2bf4(v);
    } else {
      us4 z = {0, 0, 0, 0};
      *(us4*)&sGo[r * STG + 200 + ((u - 50) << 2)] = z;  // gh K-pad
    }
  }
  {
    float brr = con_b_ih[col] + con_b_hh[col];
    float brz = con_b_ih[128 + col] + con_b_hh[128 + col];
    float bin = con_b_ih[256 + col], bhn = con_b_hh[256 + col];
    #pragma unroll
    for (int ri = 0; ri < 4; ++ri) {
      #pragma unroll
      for (int j = 0; j < 4; ++j) {
        int row = ri * 16 + qrow + j;
        float hold = bf2f(sR2[row * STH + col]);
        float rr = sigf(aRZ[0][ri][j] + brr);
        float zz = sigf(aRZ[1][ri][j] + brz);
        float nn = tanhf_(aN[ri][j] + bin + rr * (aHN[ri][j] + bhn));
        float hv = (1.f - zz) * nn + zz * hold;
        hv = fminf(fmaxf(hv, -5.f), 5.f);
        sR2[row * STH + col] = f2bf(hv);  // own col only: no cross-lane race
      }
    }
  }
  __syncthreads();  // B3

  // ---------------- ph4: co linear + reparam (f32 VALU)
  {
    int crow = tid >> 3, cn = tid & 7;
    float acc = co_b[cn];
    #pragma unroll 8
    for (int k0 = 0; k0 < 128; k0 += 4) {
      f4 hv = bf2f4(*(const us4*)&sR2[crow * STH + k0]);
      f4 wv = *(const f4*)&co_w[cn * 128 + k0];
      acc = fmaf(hv.x, wv.x, acc);
      acc = fmaf(hv.y, wv.y, acc);
      acc = fmaf(hv.z, wv.z, acc);
      acc = fmaf(hv.w, wv.w, acc);
    }
    float lv = __shfl(acc, lane + 4, 64);  // partner lane holds logvar
    if (cn < 4) {
      float stdv = __expf(0.5f * lv);
      float ov = fmaf(stdv, eps[(size_t)(rbase + crow) * 4 + cn], acc);
      sR2[crow * STH + 128 + cn] = f2bf(acc);
      sR2[crow * STH + 132 + cn] = f2bf(stdv);
      sR3[crow * STR3 + cn] = f2bf(ov);
    }
  }
  __syncthreads();  // B4

  // ---------------- ph5: flush out[:,200:336) from sR2 (coalesced span)
  for (int idx = tid; idx < 64 * 34; idx += NT) {
    int r = idx / 34, c4 = (idx - (idx / 34) * 34) << 2;
    f4 v = bf2f4(*(const us4*)&sR2[r * STH + c4]);
    *(f4*)&out[(size_t)(rbase + r) * HD + 200 + c4] = v;
  }
  __syncthreads();  // B5 (sR2 dead; sGn aliases it)

  // ---------------- ph6: gen GRU (13 col-tiles over 8 waves)
  if (tid < 256) {  // zero sGn K-pad cols 200..216
    int r = tid >> 2, q = (tid & 3) << 2;
    us4 z = {0, 0, 0, 0};
    *(us4*)&sGn[r * STG + 200 + q] = z;
  }
  {
    const ushort_t* W3 = ws + WS_W3;
    const ushort_t* W4 = ws + WS_W4;
    for (int t = w; t < 13; t += 8) {
      int c = (t << 4) + bn;  // output column (valid < 200)
      f4 gRZ[2][4], gN[4], gHN[4];
      #pragma unroll
      for (int ri = 0; ri < 4; ++ri) {
        gRZ[0][ri] = (f4){0.f, 0.f, 0.f, 0.f};
        gRZ[1][ri] = (f4){0.f, 0.f, 0.f, 0.f};
        gN[ri] = (f4){0.f, 0.f, 0.f, 0.f};
        gHN[ri] = (f4){0.f, 0.f, 0.f, 0.f};
      }
      {  // gi (K=32, A = gen_input in sR3)
        bf8 br = *(const bf8*)&W3[(size_t)(c) * 32 + kq];
        bf8 bz = *(const bf8*)&W3[(size_t)(200 + c) * 32 + kq];
        bf8 bm = *(const bf8*)&W3[(size_t)(400 + c) * 32 + kq];
        #pragma unroll
        for (int ri = 0; ri < 4; ++ri) {
          bf8 a = *(const bf8*)&sR3[(ri * 16 + bn) * STR3 + kq];
          gRZ[0][ri] = MFMA(a, br, gRZ[0][ri]);
          gRZ[1][ri] = MFMA(a, bz, gRZ[1][ri]);
          gN[ri] = MFMA(a, bm, gN[ri]);
        }
      }
      #pragma unroll
      for (int k0 = 0; k0 < 224; k0 += 32) {  // gh (K=200 padded)
        bf8 br = *(const bf8*)&W4[(size_t)(c) * 224 + k0 + kq];
        bf8 bz = *(const bf8*)&W4[(size_t)(200 + c) * 224 + k0 + kq];
        bf8 bm = *(const bf8*)&W4[(size_t)(400 + c) * 224 + k0 + kq];
        #pragma unroll
        for (int ri = 0; ri < 4; ++ri) {
          bf8 a = *(const bf8*)&sGo[(ri * 16 + bn) * STG + k0 + kq];
          gRZ[0][ri] = MFMA(a, br, gRZ[0][ri]);
          gRZ[1][ri] = MFMA(a, bz, gRZ[1][ri]);
          gHN[ri] = MFMA(a, bm, gHN[ri]);
        }
      }
      if (c < 200) {
        float brr = gen_b_ih[c] + gen_b_hh[c];
        float brz = gen_b_ih[200 + c] + gen_b_hh[200 + c];
        float bin = gen_b_ih[400 + c], bhn = gen_b_hh[400 + c];
        #pragma unroll
        for (int ri = 0; ri < 4; ++ri) {
          #pragma unroll
          for (int j = 0; j < 4; ++j) {
            int row = ri * 16 + qrow + j;
            float hold = bf2f(sGo[row * STG + c]);
            float rr = sigf(gRZ[0][ri][j] + brr);
            float zz = sigf(gRZ[1][ri][j] + brz);
            float nn = tanhf_(gN[ri][j] + bin + rr * (gHN[ri][j] + bhn));
            float hv = (1.f - zz) * nn + zz * hold;
            hv = fminf(fmaxf(hv, -5.f), 5.f);
            sGn[row * STG + c] = f2bf(hv);
          }
        }
      }
    }
  }
  __syncthreads();  // B6

  // ---------------- ph7: factor = gen_state_new @ normed_fac^T -> sR3[20:84)
  {
    const ushort_t* W5 = ws + WS_W5;
    int ri = w & 3;
    #pragma unroll
    for (int cc = 0; cc < 2; ++cc) {
      int ct = (w >> 2) + cc * 2;  // 0..3
      f4 acc = (f4){0.f, 0.f, 0.f, 0.f};
      #pragma unroll
      for (int k0 = 0; k0 < 224; k0 += 32) {
        bf8 b = *(const bf8*)&W5[(size_t)((ct << 4) + bn) * 224 + k0 + kq];
        bf8 a = *(const bf8*)&sGn[(ri * 16 + bn) * STG + k0 + kq];
        acc = MFMA(a, b, acc);
      }
      #pragma unroll
      for (int j = 0; j < 4; ++j) {
        int row = ri * 16 + qrow + j;
        sR3[row * STR3 + 20 + (ct << 4) + bn] = f2bf(acc[j]);
      }
    }
  }
  __syncthreads();  // B7

  // ---------------- ph8: final flush out[:,0:200) + out[:,336:420)
  for (int idx = tid; idx < 64 * 71; idx += NT) {
    int r = idx / 71, u = idx - (idx / 71) * 71;
    if (u < 50) {
      f4 v = bf2f4(*(const us4*)&sGn[r * STG + (u << 2)]);
      *(f4*)&out[(size_t)(rbase + r) * HD + (u << 2)] = v;
    } else {
      int u2 = u - 50;
      f4 v = bf2f4(*(const us4*)&sR3[r * STR3 + (u2 << 2)]);
      *(f4*)&out[(size_t)(rbase + r) * HD + 336 + (u2 << 2)] = v;
    }
  }
}

extern "C" void kernel_launch(void* const* d_in, const int* in_sizes, int n_in,
                              void* d_out, int out_size, void* d_ws, size_t ws_size,
                              hipStream_t stream) {
  const float* x        = (const float*)d_in[0];
  const float* h0       = (const float*)d_in[1];
  const float* eps      = (const float*)d_in[2];
  const float* gen_w_ih = (const float*)d_in[3];
  const float* gen_w_hh = (const float*)d_in[4];
  const float* gen_b_ih = (const float*)d_in[5];
  const float* gen_b_hh = (const float*)d_in[6];
  const float* con_w_ih = (const float*)d_in[7];
  const float* con_w_hh = (const float*)d_in[8];
  const float* con_b_ih = (const float*)d_in[9];
  const float* con_b_hh = (const float*)d_in[10];
  const float* co_w     = (const float*)d_in[11];
  const float* co_b     = (const float*)d_in[12];
  const float* fac_w    = (const float*)d_in[13];
  float* out = (float*)d_out;
  ushort_t* ws = (ushort_t*)d_ws;

  hipLaunchKernelGGL(prep_w, dim3(256), dim3(512), 0, stream,
                     con_w_ih, con_w_hh, gen_w_ih, gen_w_hh, ws);
  hipLaunchKernelGGL(prep_fac, dim3(64), dim3(64), 0, stream, fac_w, ws);

  int nrows = in_sizes[2] / 4;  // eps is (B,4)
  int grid = nrows / RT;        // 1024
  hipLaunchKernelGGL(decoder_kernel, dim3(grid), dim3(NT), 0, stream,
                     x, h0, eps, gen_b_ih, gen_b_hh, con_b_ih, con_b_hh,
                     co_w, co_b, ws, out);
}